// Round 5
// baseline (765.412 us; speedup 1.0000x reference)
//
#include <hip/hip_runtime.h>
#include <math.h>

#define BSZ 4
#define NN 1024
#define BH 8
#define DD 64
#define MM 2048
#define KRET 16
#define CC 64
#define NEGV -1000000000.0f
#define EPSV 1e-8f
#define SMAXV 4.0f
#define BUDGETV 512.0f

// ws layout (float-element offsets)
#define WS_NOV  0         // [32][1024] novelty
#define WS_CI   32768     // int [32][64] candidate indices
#define WS_CW   34816     // [32][64] cand_weight
#define WS_CKN  36864     // [32][64][64] unit-normalized cand_K
#define WS_CV   167936    // [32][64][64] cand_V
#define WS_PMAX 299008    // [32][64][16] slot-softmax partial max
#define WS_PSUM 331776    // [32][64][16] slot-softmax partial sumexp
#define WS_TOTS 364544    // [32] new_S totals (memset to 0 each call)

// ---------------------------------------------------------------------------
// Kernel 1: scores = q.K^T with top-16 + softmax + P.V, sim = q_nov.K^T max,
// novelty output.
// R7: R4's regression at HIGHER occupancy proved k1 is staging-stall bound:
// per tile, global->LDS K staging exposed ~300-500cyc of latency behind a
// barrier, in lockstep for all waves (R2/R4 both doubled #stagings and both
// lost). Revert to R3 shape (64-row tile, R=2 x C=8 regtile, 476us best) and
// DOUBLE-BUFFER K/S: prefetch tile mt+1 into regs before compute(mt), write
// to alt LDS buffer after, ONE barrier per tile. Latency hides under the
// ~4000cyc FMA section. LDS 68.5KB -> still 2 blocks/CU.
// ---------------------------------------------------------------------------
__global__ __launch_bounds__(256, 2)
void k1_read(const float* __restrict__ q, const float* __restrict__ qn,
             const float* __restrict__ surprise, const float* __restrict__ wnov,
             const float* __restrict__ emK, const float* __restrict__ emV,
             const float* __restrict__ emS, float* __restrict__ out,
             float* __restrict__ ws)
{
    const int sb = blockIdx.x;            // 0..31  (s*8+b)
    const int s = sb >> 3, b = sb & 7;
    const int n0 = blockIdx.y << 6;       // n-tile of 64
    const int t = threadIdx.x;
    const int rg = t >> 3;                // row-group 0..31
    const int cg = t & 7;                 // col sub-lane 0..7
    const int r0 = rg << 1;               // this thread's 2 rows

    __shared__ float qs[64][68];
    __shared__ float qsn[64][68];
    __shared__ float Kt[2][64][68];
    __shared__ float Sm[2][64];

    const float* Kb = emK + (size_t)sb*MM*DD;
    const float* Sb = emS + (size_t)sb*MM;

    // stage q / q_nov tile (64 rows x 64 floats) + K tile 0
    #pragma unroll
    for (int k = 0; k < 4; ++k) {
        const int fi = t + (k << 8);
        const int row = fi >> 4;
        const int col = (fi & 15) << 2;
        const size_t qb = (((size_t)s*NN + n0 + row)*BH + b)*DD + col;
        *(float4*)&qs[row][col]  = *(const float4*)&q[qb];
        *(float4*)&qsn[row][col] = *(const float4*)&qn[qb];
        *(float4*)&Kt[0][row][col] = *(const float4*)&Kb[(size_t)row*DD + col];
    }
    if (t < 64) Sm[0][t] = Sb[t];

    // sorted-descending top-16 lists (lv[rr][0] = max .. lv[rr][15] = min)
    float lv[2][16]; int li[2][16];
    float nsim[2];
    #pragma unroll
    for (int rr = 0; rr < 2; ++rr) {
        #pragma unroll
        for (int i = 0; i < 16; ++i) { lv[rr][i] = -3.0e38f; li[rr][i] = 0; }
        nsim[rr] = -3.0e38f;
    }

    __syncthreads();

// compare-exchange on batch arrays (desc: max to x)
#define CEB(x, y) { const bool sw_ = bv[y] > bv[x];                       \
    const float f0_ = sw_ ? bv[y] : bv[x]; const float f1_ = sw_ ? bv[x] : bv[y]; \
    bv[x] = f0_; bv[y] = f1_;                                             \
    const int i0_ = sw_ ? bi[y] : bi[x]; const int i1_ = sw_ ? bi[x] : bi[y]; \
    bi[x] = i0_; bi[y] = i1_; }
// compare-exchange on the list (desc)
#define CEL(x, y) { const bool sw_ = lv[rr][y] > lv[rr][x];               \
    const float f0_ = sw_ ? lv[rr][y] : lv[rr][x];                        \
    const float f1_ = sw_ ? lv[rr][x] : lv[rr][y];                        \
    lv[rr][x] = f0_; lv[rr][y] = f1_;                                     \
    const int i0_ = sw_ ? li[rr][y] : li[rr][x];                          \
    const int i1_ = sw_ ? li[rr][x] : li[rr][y];                          \
    li[rr][x] = i0_; li[rr][y] = i1_; }

    #pragma unroll 1
    for (int mt = 0; mt < MM/64; ++mt) {
        const int cur = mt & 1;

        // ---- prefetch next K/S tile into registers (latency hidden by FMAs)
        float4 kp[4]; float sp;
        {
            const int nxt = (mt + 1 < MM/64) ? mt + 1 : mt;  // tail: harmless dup
            #pragma unroll
            for (int k = 0; k < 4; ++k) {
                const int fi = t + (k << 8);
                const int row = fi >> 4;
                const int col = (fi & 15) << 2;
                kp[k] = *(const float4*)&Kb[((size_t)(nxt*64 + row))*DD + col];
            }
            sp = (t < 64) ? Sb[nxt*64 + t] : 0.f;
        }

        // ---- compute on current buffer
        float acc[2][8], accn[2][8];
        #pragma unroll
        for (int rr = 0; rr < 2; ++rr)
            #pragma unroll
            for (int j = 0; j < 8; ++j) { acc[rr][j] = 0.f; accn[rr][j] = 0.f; }

        #pragma unroll 2
        for (int ch = 0; ch < 16; ++ch) {
            const float4 qa  = *(const float4*)&qs[r0][ch << 2];
            const float4 na  = *(const float4*)&qsn[r0][ch << 2];
            const float4 qb4 = *(const float4*)&qs[r0 + 1][ch << 2];
            const float4 nb4 = *(const float4*)&qsn[r0 + 1][ch << 2];
            #pragma unroll
            for (int j = 0; j < 8; ++j) {
                const float4 k4 = *(const float4*)&Kt[cur][cg + (j << 3)][ch << 2];
                acc[0][j]  += qa.x*k4.x  + qa.y*k4.y  + qa.z*k4.z  + qa.w*k4.w;
                accn[0][j] += na.x*k4.x  + na.y*k4.y  + na.z*k4.z  + na.w*k4.w;
                acc[1][j]  += qb4.x*k4.x + qb4.y*k4.y + qb4.z*k4.z + qb4.w*k4.w;
                accn[1][j] += nb4.x*k4.x + nb4.y*k4.y + nb4.z*k4.z + nb4.w*k4.w;
            }
        }

        // active-mask + novelty preamble, then batch top-16 merge per row
        float sq[2][8];
        #pragma unroll
        for (int j = 0; j < 8; ++j) {
            const int ml = cg + (j << 3);
            const bool act = Sm[cur][ml] > 0.f;
            sq[0][j] = act ? acc[0][j] : NEGV;
            sq[1][j] = act ? acc[1][j] : NEGV;
            nsim[0] = fmaxf(nsim[0], act ? accn[0][j] : -1.0f);
            nsim[1] = fmaxf(nsim[1], act ? accn[1][j] : -1.0f);
        }

        #pragma unroll
        for (int rr = 0; rr < 2; ++rr) {
            float bmax = sq[rr][0];
            #pragma unroll
            for (int j = 1; j < 8; ++j) bmax = fmaxf(bmax, sq[rr][j]);
            if (bmax > lv[rr][15]) {
                float bv[8]; int bi[8];
                #pragma unroll
                for (int j = 0; j < 8; ++j) {
                    bv[j] = sq[rr][j];
                    bi[j] = mt*64 + cg + (j << 3);
                }
                // Batcher OEMS-8, descending (19 CE)
                CEB(0,1) CEB(2,3) CEB(4,5) CEB(6,7)
                CEB(0,2) CEB(1,3) CEB(4,6) CEB(5,7)
                CEB(1,2) CEB(5,6)
                CEB(0,4) CEB(1,5) CEB(2,6) CEB(3,7)
                CEB(2,4) CEB(3,5)
                CEB(1,2) CEB(3,4) CEB(5,6)
                // half-cleaner keep-merge: new bottom-8 = top-8 of
                // {old bottom-8 ∪ batch}  (exact top-16 multiset)
                #pragma unroll
                for (int i = 0; i < 8; ++i) {
                    const bool tk = bv[7-i] > lv[rr][8+i];
                    if (tk) { lv[rr][8+i] = bv[7-i]; li[rr][8+i] = bi[7-i]; }
                }
                // bottom half is bitonic -> sort desc (12 CE)
                CEL(8,12) CEL(9,13) CEL(10,14) CEL(11,15)
                CEL(8,10) CEL(9,11) CEL(12,14) CEL(13,15)
                CEL(8,9)  CEL(10,11) CEL(12,13) CEL(14,15)
                // merge two sorted-desc halves -> fully sorted 16 (32 CE)
                CEL(0,15) CEL(1,14) CEL(2,13) CEL(3,12)
                CEL(4,11) CEL(5,10) CEL(6,9)  CEL(7,8)
                CEL(0,4) CEL(1,5) CEL(2,6) CEL(3,7)
                CEL(0,2) CEL(1,3) CEL(4,6) CEL(5,7)
                CEL(0,1) CEL(2,3) CEL(4,5) CEL(6,7)
                CEL(8,12) CEL(9,13) CEL(10,14) CEL(11,15)
                CEL(8,10) CEL(9,11) CEL(12,14) CEL(13,15)
                CEL(8,9)  CEL(10,11) CEL(12,13) CEL(14,15)
            }
        }

        // ---- write prefetched tile to alternate buffer, single barrier
        #pragma unroll
        for (int k = 0; k < 4; ++k) {
            const int fi = t + (k << 8);
            const int row = fi >> 4;
            const int col = (fi & 15) << 2;
            *(float4*)&Kt[cur ^ 1][row][col] = kp[k];
        }
        if (t < 64) Sm[cur ^ 1][t] = sp;
        __syncthreads();
    }
#undef CEB
#undef CEL

    // ---- per-row merge of 8 sorted lists -> softmax weights + P.V ----
    const float* Vb = emV + (size_t)sb*MM*DD;

    #pragma unroll
    for (int rr = 0; rr < 2; ++rr) {
        float m0 = 0.f, den = 0.f, wkA = 0.f, wkB = 0.f;
        int ikA = 0, ikB = 0;
        #pragma unroll 1
        for (int k = 0; k < 16; ++k) {
            float cb = lv[rr][0]; int ci2 = li[rr][0]; int key = cg;
            #pragma unroll
            for (int off = 4; off >= 1; off >>= 1) {
                const float ov = __shfl_xor(cb, off, 8);
                const int   ok = __shfl_xor(key, off, 8);
                const int   oi = __shfl_xor(ci2, off, 8);
                if (ov > cb || (ov == cb && ok < key)) { cb = ov; key = ok; ci2 = oi; }
            }
            if (k == 0) m0 = cb;
            const float e = __expf(cb - m0);
            den += e;
            if (key == cg) {   // this lane's head won: pop it
                #pragma unroll
                for (int i = 0; i < 15; ++i) {
                    lv[rr][i] = lv[rr][i+1]; li[rr][i] = li[rr][i+1];
                }
            }
            if ((k & 7) == cg) {
                if (k < 8) { wkA = e; ikA = ci2; }
                else       { wkB = e; ikB = ci2; }
            }
        }

        // novelty: max sim across the group
        float ns = nsim[rr];
        #pragma unroll
        for (int off = 4; off >= 1; off >>= 1)
            ns = fmaxf(ns, __shfl_xor(ns, off, 8));

        // P.V gather: this lane covers d in [cg*8, cg*8+8)
        const float invden = 1.0f / den;
        float4 oA = make_float4(0.f, 0.f, 0.f, 0.f);
        float4 oB = make_float4(0.f, 0.f, 0.f, 0.f);
        #pragma unroll 1
        for (int k = 0; k < 16; ++k) {
            const bool hi = k >= 8;
            const float wsrc = hi ? wkB : wkA;
            const int   isrc = hi ? ikB : ikA;
            const float wv = __shfl(wsrc, k & 7, 8);
            const int   iv = __shfl(isrc, k & 7, 8);
            const float* vp = Vb + (size_t)iv*DD + (cg << 3);
            const float4 va  = *(const float4*)vp;
            const float4 vb2 = *(const float4*)(vp + 4);
            oA.x += wv*va.x;  oA.y += wv*va.y;  oA.z += wv*va.z;  oA.w += wv*va.w;
            oB.x += wv*vb2.x; oB.y += wv*vb2.y; oB.z += wv*vb2.z; oB.w += wv*vb2.w;
        }
        oA.x *= invden; oA.y *= invden; oA.z *= invden; oA.w *= invden;
        oB.x *= invden; oB.y *= invden; oB.z *= invden; oB.w *= invden;
        const size_t ob = (((size_t)s*NN + n0 + r0 + rr)*BH + b)*DD + (cg << 3);
        *(float4*)&out[ob]     = oA;
        *(float4*)&out[ob + 4] = oB;

        if (cg == 0) {
            const int ni = ((s*NN + n0 + r0 + rr)*BH) + b;
            const float w = wnov[ni], su = surprise[ni];
            ws[WS_NOV + sb*NN + n0 + r0 + rr] =
                w*su + (1.f - w)*(1.f - fmaxf(ns, 0.f));
        }
    }
}

// ---------------------------------------------------------------------------
// Kernel 2: per (s,b) top-64 of novelty over N=1024 + cand_weight.
// Single-wave tournament (no barriers).
// ---------------------------------------------------------------------------
__global__ __launch_bounds__(64)
void k2_topc(float* __restrict__ ws)
{
    const int sb = blockIdx.x;
    const int lane = threadIdx.x;          // 0..63
    float av[16]; int ai[16];
    const int base = WS_NOV + sb*NN + lane*16;
    #pragma unroll
    for (int j = 0; j < 16; ++j) { av[j] = ws[base + j]; ai[j] = lane*16 + j; }

    // odd-even transposition sort: descending value, ascending index on ties
    #pragma unroll
    for (int pass = 0; pass < 16; ++pass) {
        #pragma unroll
        for (int i = (pass & 1); i + 1 < 16; i += 2) {
            const bool sw = (av[i] < av[i+1]) ||
                            (av[i] == av[i+1] && ai[i] > ai[i+1]);
            const float t0 = sw ? av[i+1] : av[i];
            const float t1 = sw ? av[i]   : av[i+1];
            av[i] = t0; av[i+1] = t1;
            const int u0 = sw ? ai[i+1] : ai[i];
            const int u1 = sw ? ai[i]   : ai[i+1];
            ai[i] = u0; ai[i+1] = u1;
        }
    }

    float kv = 0.f; int ki = 0;
    #pragma unroll 1
    for (int k = 0; k < CC; ++k) {
        float lv2 = av[0]; int key = lane;
        #pragma unroll
        for (int off = 32; off >= 1; off >>= 1) {
            const float ov = __shfl_xor(lv2, off, 64);
            const int   ok = __shfl_xor(key, off, 64);
            if (ov > lv2 || (ov == lv2 && ok < key)) { lv2 = ov; key = ok; }
        }
        const int widx = __shfl(ai[0], key, 64);
        if (lane == k) { kv = lv2; ki = widx; }
        if (lane == key) {
            #pragma unroll
            for (int i = 0; i < 15; ++i) { av[i] = av[i+1]; ai[i] = ai[i+1]; }
            av[15] = -3.0e38f;
        }
    }

    float sum = kv;
    #pragma unroll
    for (int off = 32; off >= 1; off >>= 1) sum += __shfl_xor(sum, off, 64);
    ((int*)ws)[WS_CI + sb*CC + lane] = ki;
    ws[WS_CW + sb*CC + lane] = kv / (sum + EPSV);
}

// ---------------------------------------------------------------------------
// Kernel 3a: gather cand_K/cand_V, unit-normalize cand_K
// ---------------------------------------------------------------------------
__global__ __launch_bounds__(256)
void k3a_gather(const float* __restrict__ qn, const float* __restrict__ vn,
                float* __restrict__ ws)
{
    const int sb = blockIdx.x; const int s = sb >> 3, b = sb & 7;
    const int t = threadIdx.x;
    const int cc = t >> 2, qd = t & 3;
    const int idx = ((const int*)ws)[WS_CI + sb*CC + cc];
    const size_t base = (((size_t)s*NN + idx)*BH + b)*DD + qd*16;

    float4 a[4]; float ss = 0.f;
    #pragma unroll
    for (int k = 0; k < 4; ++k) {
        a[k] = *(const float4*)&qn[base + (k << 2)];
        ss += a[k].x*a[k].x + a[k].y*a[k].y + a[k].z*a[k].z + a[k].w*a[k].w;
    }
    #pragma unroll
    for (int off = 2; off >= 1; off >>= 1) ss += __shfl_xor(ss, off, 4);
    const float sc = 1.0f / fmaxf(sqrtf(ss), EPSV);

    float* ck = ws + WS_CKN + ((size_t)sb*CC + cc)*DD + qd*16;
    float* cv = ws + WS_CV  + ((size_t)sb*CC + cc)*DD + qd*16;
    #pragma unroll
    for (int k = 0; k < 4; ++k) {
        float4 o = a[k]; o.x *= sc; o.y *= sc; o.z *= sc; o.w *= sc;
        *(float4*)&ck[k << 2] = o;
        *(float4*)&cv[k << 2] = *(const float4*)&vn[base + (k << 2)];
    }
}

// ---------------------------------------------------------------------------
// Kernel 3b: slot-softmax partial stats.
// grid (32,16); each block = 64 cands x 128 m GEMM tile with K staged once
// in LDS; online-softmax partials to ws, combined in k3c's prologue.
// ---------------------------------------------------------------------------
__global__ __launch_bounds__(256)
void k3b_stats(const float* __restrict__ emK, const float* __restrict__ emS,
               const float* __restrict__ tau, const float* __restrict__ wwp,
               float* __restrict__ ws)
{
    const int sb = blockIdx.x;
    const int mc = blockIdx.y;           // m-chunk of 128
    const int t = threadIdx.x;
    const int rg = t >> 3, cg = t & 7;
    const int c0 = rg << 1;

    __shared__ float ckL[64][68];
    __shared__ float Kt[64][68];
    __shared__ float Sm[64];

    #pragma unroll
    for (int k = 0; k < 4; ++k) {
        const int fi = t + (k << 8);
        const int row = fi >> 4;
        const int col = (fi & 15) << 2;
        *(float4*)&ckL[row][col] =
            *(const float4*)&ws[WS_CKN + ((size_t)sb*CC + row)*DD + col];
    }

    const float invt = 1.0f / fmaxf(tau[sb], 0.01f);
    const float wwv = wwp[sb];
    const float* Kb = emK + (size_t)sb*MM*DD;
    const float* Sb = emS + (size_t)sb*MM;

    float rmax[2] = {-3.0e38f, -3.0e38f};
    float rsum[2] = {0.f, 0.f};

    #pragma unroll 1
    for (int tt = 0; tt < 2; ++tt) {
        const int mb = (mc << 7) + (tt << 6);
        __syncthreads();
        #pragma unroll
        for (int k = 0; k < 4; ++k) {
            const int fi = t + (k << 8);
            const int row = fi >> 4;
            const int col = (fi & 15) << 2;
            *(float4*)&Kt[row][col] = *(const float4*)&Kb[((size_t)(mb + row))*DD + col];
        }
        if (t < 64) Sm[t] = Sb[mb + t];
        __syncthreads();

        float acc[2][8];
        #pragma unroll
        for (int rr = 0; rr < 2; ++rr)
            #pragma unroll
            for (int j = 0; j < 8; ++j) acc[rr][j] = 0.f;

        #pragma unroll 2
        for (int ch = 0; ch < 16; ++ch) {
            const float4 ca = *(const float4*)&ckL[c0][ch << 2];
            const float4 cb = *(const float4*)&ckL[c0 + 1][ch << 2];
            #pragma unroll
            for (int j = 0; j < 8; ++j) {
                const float4 k4 = *(const float4*)&Kt[cg + (j << 3)][ch << 2];
                acc[0][j] += ca.x*k4.x + ca.y*k4.y + ca.z*k4.z + ca.w*k4.w;
                acc[1][j] += cb.x*k4.x + cb.y*k4.y + cb.z*k4.z + cb.w*k4.w;
            }
        }

        #pragma unroll
        for (int rr = 0; rr < 2; ++rr) {
            float z[8];
            #pragma unroll
            for (int j = 0; j < 8; ++j)
                z[j] = (acc[rr][j] - wwv*Sm[cg + (j << 3)]) * invt;
            float tmax = z[0];
            #pragma unroll
            for (int j = 1; j < 8; ++j) tmax = fmaxf(tmax, z[j]);
            #pragma unroll
            for (int off = 4; off >= 1; off >>= 1)
                tmax = fmaxf(tmax, __shfl_xor(tmax, off, 8));
            const float nm = fmaxf(rmax[rr], tmax);
            float ts = 0.f;
            #pragma unroll
            for (int j = 0; j < 8; ++j) ts += __expf(z[j] - nm);
            #pragma unroll
            for (int off = 4; off >= 1; off >>= 1) ts += __shfl_xor(ts, off, 8);
            rsum[rr] = rsum[rr]*__expf(rmax[rr] - nm) + ts;
            rmax[rr] = nm;
        }
    }
    if (cg == 0) {
        #pragma unroll
        for (int rr = 0; rr < 2; ++rr) {
            ws[WS_PMAX + ((size_t)sb*CC + c0 + rr)*16 + mc] = rmax[rr];
            ws[WS_PSUM + ((size_t)sb*CC + c0 + rr)*16 + mc] = rsum[rr];
        }
    }
}

// ---------------------------------------------------------------------------
// Kernel 3c: per (s,b, 64-m tile): alpha, alpha_per_slot, blends, updates
// ---------------------------------------------------------------------------
__global__ __launch_bounds__(256)
void k3c_write(const float* __restrict__ emK, const float* __restrict__ emV,
               const float* __restrict__ emS, const float* __restrict__ emA,
               const float* __restrict__ gem, const float* __restrict__ tau,
               const float* __restrict__ dec, const float* __restrict__ wwp,
             float* __restrict__ outK, float* __restrict__ outV,
             float* __restrict__ outS, float* __restrict__ outA,
             float* __restrict__ ws)
{
    const int sb = blockIdx.x; const int m0 = blockIdx.y << 6;
    const int t = threadIdx.x;
    __shared__ float ckn[64][68];
    __shared__ float cvv[64][68];
    __shared__ float alphaT[64][64];   // [c][m]
    __shared__ float apsL[64];
    __shared__ float psum[4][64];
    __shared__ float pn[4][64];
    __shared__ float mx[64], gs[64], Sl[64];

    const float gv  = gem[sb];
    const float invt = 1.0f / fmaxf(tau[sb], 0.01f);
    const float wwv = wwp[sb];
    const float dcv = dec[sb];

    #pragma unroll
    for (int k = 0; k < 4; ++k) {
        const int fid = t + (k << 8);
        const int row = fid >> 4;
        const int col = (fid & 15) << 2;
        *(float4*)&ckn[row][col] = *(const float4*)&ws[WS_CKN + ((size_t)sb*CC + row)*DD + col];
        *(float4*)&cvv[row][col] = *(const float4*)&ws[WS_CV  + ((size_t)sb*CC + row)*DD + col];
    }
    if (t < 64) {
        // combine slot-softmax partials
        float mg = -3.0e38f;
        #pragma unroll
        for (int p = 0; p < 16; ++p)
            mg = fmaxf(mg, ws[WS_PMAX + ((size_t)sb*CC + t)*16 + p]);
        float sg = 0.f;
        #pragma unroll
        for (int p = 0; p < 16; ++p)
            sg += ws[WS_PSUM + ((size_t)sb*CC + t)*16 + p] *
                  __expf(ws[WS_PMAX + ((size_t)sb*CC + t)*16 + p] - mg);
        const float cw = ws[WS_CW + sb*CC + t];
        mx[t] = mg;
        gs[t] = gv * cw / sg;
        Sl[t] = emS[(size_t)sb*MM + m0 + t];
    }
    __syncthreads();

    const int m = t & 63, w = t >> 6;

    // step 1: alphaT[c][m] for this wave's 16 c's
    {
        float acc[16];
        #pragma unroll
        for (int i = 0; i < 16; ++i) acc[i] = 0.f;
        const float* Krow = emK + ((size_t)sb*MM + m0 + m)*DD;
        #pragma unroll 4
        for (int ch = 0; ch < 16; ++ch) {
            const float4 k4 = *(const float4*)&Krow[ch << 2];
            #pragma unroll
            for (int i = 0; i < 16; ++i) {
                const float4 c4 = *(const float4*)&ckn[(w << 4) + i][ch << 2];
                acc[i] += k4.x*c4.x + k4.y*c4.y + k4.z*c4.z + k4.w*c4.w;
            }
        }
        const float Sv = Sl[m];
        #pragma unroll
        for (int i = 0; i < 16; ++i) {
            const int c = (w << 4) + i;
            const float zz = (acc[i] - wwv*Sv) * invt;
            alphaT[c][m] = gs[c] * __expf(zz - mx[c]);
        }
    }
    __syncthreads();

    // step 2: alpha_per_slot
    {
        float p = 0.f;
        #pragma unroll
        for (int i = 0; i < 16; ++i) p += alphaT[(w << 4) + i][m];
        psum[w][m] = p;
    }
    __syncthreads();
    if (t < 64) apsL[t] = (psum[0][t] + psum[1][t]) + (psum[2][t] + psum[3][t]);
    __syncthreads();

    // step 3: blends — this thread covers d in [w*16, w*16+16)
    float bk[16], bv[16];
    #pragma unroll
    for (int i = 0; i < 16; ++i) { bk[i] = 0.f; bv[i] = 0.f; }
    for (int cI = 0; cI < 64; ++cI) {
        const float a = alphaT[cI][m];
        #pragma unroll
        for (int k = 0; k < 4; ++k) {
            const float4 c4 = *(const float4*)&ckn[cI][(w << 4) + (k << 2)];
            const float4 v4 = *(const float4*)&cvv[cI][(w << 4) + (k << 2)];
            bk[(k<<2)+0] += a*c4.x; bk[(k<<2)+1] += a*c4.y;
            bk[(k<<2)+2] += a*c4.z; bk[(k<<2)+3] += a*c4.w;
            bv[(k<<2)+0] += a*v4.x; bv[(k<<2)+1] += a*v4.y;
            bv[(k<<2)+2] += a*v4.z; bv[(k<<2)+3] += a*v4.w;
        }
    }

    // step 4: normalize + update
    const float aps = apsL[m];
    const float idn = 1.0f / fmaxf(aps, EPSV);
    float ssq = 0.f;
    #pragma unroll
    for (int i = 0; i < 16; ++i) { bk[i] *= idn; bv[i] *= idn; ssq += bk[i]*bk[i]; }
    pn[w][m] = ssq;
    __syncthreads();
    const float nrm2 = (pn[0][m] + pn[1][m]) + (pn[2][m] + pn[3][m]);
    const float innv = 1.0f / fmaxf(sqrtf(nrm2), EPSV);
    const float ae = fminf(aps, 1.0f);
    const float oma = 1.0f - ae;
    const bool upd = aps > EPSV;
    const size_t gb = ((size_t)sb*MM + m0 + m)*DD + (w << 4);
    #pragma unroll
    for (int kq = 0; kq < 4; ++kq) {
        const float4 kk = *(const float4*)&emK[gb + (kq << 2)];
        const float4 vv = *(const float4*)&emV[gb + (kq << 2)];
        float4 nk, nv2;
        if (upd) {
            nk.x = oma*kk.x + ae*(bk[(kq<<2)+0]*innv);
            nk.y = oma*kk.y + ae*(bk[(kq<<2)+1]*innv);
            nk.z = oma*kk.z + ae*(bk[(kq<<2)+2]*innv);
            nk.w = oma*kk.w + ae*(bk[(kq<<2)+3]*innv);
            nv2.x = oma*vv.x + ae*bv[(kq<<2)+0];
            nv2.y = oma*vv.y + ae*bv[(kq<<2)+1];
            nv2.z = oma*vv.z + ae*bv[(kq<<2)+2];
            nv2.w = oma*vv.w + ae*bv[(kq<<2)+3];
        } else { nk = kk; nv2 = vv; }
        *(float4*)&outK[gb + (kq << 2)] = nk;
        *(float4*)&outV[gb + (kq << 2)] = nv2;
    }
    if (w == 0) {
        const float pre = fminf(fmaxf(Sl[m] + aps, 0.f), SMAXV) * dcv;
        outS[(size_t)sb*MM + m0 + m] = pre;
        outA[(size_t)sb*MM + m0 + m] = emA[(size_t)sb*MM + m0 + m] * (1.0f - aps);
        float tot = pre;
        #pragma unroll
        for (int off = 32; off >= 1; off >>= 1) tot += __shfl_xor(tot, off, 64);
        if (m == 0) atomicAdd(&ws[WS_TOTS + sb], tot);
    }
}

// ---------------------------------------------------------------------------
// Kernel 4: budget rescale of new_S
// ---------------------------------------------------------------------------
__global__ __launch_bounds__(256)
void k4_budget(float* __restrict__ outS, const float* __restrict__ ws)
{
    const int sb = blockIdx.x;
    const float sc = fminf(1.0f, BUDGETV / (ws[WS_TOTS + sb] + EPSV));
    for (int m = threadIdx.x; m < MM; m += 256)
        outS[(size_t)sb*MM + m] *= sc;
}

extern "C" void kernel_launch(void* const* d_in, const int* in_sizes, int n_in,
                              void* d_out, int out_size, void* d_ws, size_t ws_size,
                              hipStream_t stream)
{
    const float* q   = (const float*)d_in[0];
    const float* qnv = (const float*)d_in[1];
    const float* vnv = (const float*)d_in[2];
    const float* sur = (const float*)d_in[3];
    const float* wn  = (const float*)d_in[4];
    const float* gem = (const float*)d_in[5];
    const float* tau = (const float*)d_in[6];
    const float* dec = (const float*)d_in[7];
    const float* wwp = (const float*)d_in[8];
    const float* emK = (const float*)d_in[9];
    const float* emV = (const float*)d_in[10];
    const float* emS = (const float*)d_in[11];
    const float* emA = (const float*)d_in[12];

    float* out  = (float*)d_out;
    float* outK = out + 2097152;
    float* outV = out + 6291456;
    float* outS = out + 10485760;
    float* outA = out + 10551296;
    float* ws = (float*)d_ws;

    hipMemsetAsync((char*)d_ws + WS_TOTS*sizeof(float), 0, 32*sizeof(float), stream);

    k1_read<<<dim3(32, 16), 256, 0, stream>>>(q, qnv, sur, wn, emK, emV, emS, out, ws);
    k2_topc<<<32, 64, 0, stream>>>(ws);
    k3a_gather<<<32, 256, 0, stream>>>(qnv, vnv, ws);
    k3b_stats<<<dim3(32, 16), 256, 0, stream>>>(emK, emS, tau, wwp, ws);
    k3c_write<<<dim3(32, 32), 256, 0, stream>>>(emK, emV, emS, emA, gem, tau, dec, wwp,
                                                outK, outV, outS, outA, ws);
    k4_budget<<<32, 256, 0, stream>>>(outS, ws);
}

// Round 6
// 636.161 us; speedup vs baseline: 1.2032x; 1.2032x over previous
//
#include <hip/hip_runtime.h>
#include <math.h>

#define BSZ 4
#define NN 1024
#define BH 8
#define DD 64
#define MM 2048
#define KRET 16
#define CC 64
#define NEGV -1000000000.0f
#define EPSV 1e-8f
#define SMAXV 4.0f
#define BUDGETV 512.0f

#define FMA4(a4, b4, acc) \
    fmaf((a4).w, (b4).w, fmaf((a4).z, (b4).z, fmaf((a4).y, (b4).y, fmaf((a4).x, (b4).x, (acc)))))

// ws layout (float-element offsets)
#define WS_NOV  0         // [32][1024] novelty
#define WS_CI   32768     // int [32][64] candidate indices
#define WS_CW   34816     // [32][64] cand_weight
#define WS_CKN  36864     // [32][64][64] unit-normalized cand_K
#define WS_CV   167936    // [32][64][64] cand_V
#define WS_PMAX 299008    // [32][64][16] slot-softmax partial max
#define WS_PSUM 331776    // [32][64][16] slot-softmax partial sumexp
#define WS_TOTS 364544    // [32] new_S totals (memset to 0 each call)

// ---------------------------------------------------------------------------
// Kernel 1: scores = q.K^T with top-16 + softmax + P.V, sim = q_nov.K^T max,
// novelty output.
// R8: k1 is VALU-issue bound (R3 calibration: inst-cut -> time-cut 1:1;
// VALUBusy*dur = 374us/SIMD vs ~154us modeled minimum). The gap points at
// FMA formation: `acc += a.x*b.x+a.y*b.y+...` can compile to 5-8 insts per
// 4 MACs. Force 4-fma chains with explicit fmaf everywhere hot. R5's dbuf
// was null -> reverted to R3's simple staging (best measured: 476us).
// ---------------------------------------------------------------------------
__global__ __launch_bounds__(256, 2)
void k1_read(const float* __restrict__ q, const float* __restrict__ qn,
             const float* __restrict__ surprise, const float* __restrict__ wnov,
             const float* __restrict__ emK, const float* __restrict__ emV,
             const float* __restrict__ emS, float* __restrict__ out,
             float* __restrict__ ws)
{
    const int sb = blockIdx.x;            // 0..31  (s*8+b)
    const int s = sb >> 3, b = sb & 7;
    const int n0 = blockIdx.y << 6;       // n-tile of 64
    const int t = threadIdx.x;
    const int rg = t >> 3;                // row-group 0..31
    const int cg = t & 7;                 // col sub-lane 0..7
    const int r0 = rg << 1;               // this thread's 2 rows

    __shared__ float qs[64][68];
    __shared__ float qsn[64][68];
    __shared__ float Kt[64][68];
    __shared__ float Sm[64];

    // stage q / q_nov tile: 64 rows x 64 floats
    #pragma unroll
    for (int k = 0; k < 4; ++k) {
        const int fi = t + (k << 8);
        const int row = fi >> 4;
        const int col = (fi & 15) << 2;
        const size_t qb = (((size_t)s*NN + n0 + row)*BH + b)*DD + col;
        *(float4*)&qs[row][col]  = *(const float4*)&q[qb];
        *(float4*)&qsn[row][col] = *(const float4*)&qn[qb];
    }

    // sorted-descending top-16 lists (lv[rr][0] = max .. lv[rr][15] = min)
    float lv[2][16]; int li[2][16];
    float nsim[2];
    #pragma unroll
    for (int rr = 0; rr < 2; ++rr) {
        #pragma unroll
        for (int i = 0; i < 16; ++i) { lv[rr][i] = -3.0e38f; li[rr][i] = 0; }
        nsim[rr] = -3.0e38f;
    }

    const float* Kb = emK + (size_t)sb*MM*DD;
    const float* Sb = emS + (size_t)sb*MM;

// compare-exchange on batch arrays (desc: max to x)
#define CEB(x, y) { const bool sw_ = bv[y] > bv[x];                       \
    const float f0_ = sw_ ? bv[y] : bv[x]; const float f1_ = sw_ ? bv[x] : bv[y]; \
    bv[x] = f0_; bv[y] = f1_;                                             \
    const int i0_ = sw_ ? bi[y] : bi[x]; const int i1_ = sw_ ? bi[x] : bi[y]; \
    bi[x] = i0_; bi[y] = i1_; }
// compare-exchange on the list (desc)
#define CEL(x, y) { const bool sw_ = lv[rr][y] > lv[rr][x];               \
    const float f0_ = sw_ ? lv[rr][y] : lv[rr][x];                        \
    const float f1_ = sw_ ? lv[rr][x] : lv[rr][y];                        \
    lv[rr][x] = f0_; lv[rr][y] = f1_;                                     \
    const int i0_ = sw_ ? li[rr][y] : li[rr][x];                          \
    const int i1_ = sw_ ? li[rr][x] : li[rr][y];                          \
    li[rr][x] = i0_; li[rr][y] = i1_; }

    #pragma unroll 1
    for (int mt = 0; mt < MM/64; ++mt) {
        __syncthreads();   // protect Kt/Sm from previous-iter readers
        #pragma unroll
        for (int k = 0; k < 4; ++k) {
            const int fi = t + (k << 8);
            const int row = fi >> 4;
            const int col = (fi & 15) << 2;
            *(float4*)&Kt[row][col] =
                *(const float4*)&Kb[((size_t)(mt*64 + row))*DD + col];
        }
        if (t < 64) Sm[t] = Sb[mt*64 + t];
        __syncthreads();

        float acc[2][8], accn[2][8];
        #pragma unroll
        for (int rr = 0; rr < 2; ++rr)
            #pragma unroll
            for (int j = 0; j < 8; ++j) { acc[rr][j] = 0.f; accn[rr][j] = 0.f; }

        #pragma unroll 4
        for (int ch = 0; ch < 16; ++ch) {
            const float4 qa  = *(const float4*)&qs[r0][ch << 2];
            const float4 na  = *(const float4*)&qsn[r0][ch << 2];
            const float4 qb4 = *(const float4*)&qs[r0 + 1][ch << 2];
            const float4 nb4 = *(const float4*)&qsn[r0 + 1][ch << 2];
            #pragma unroll
            for (int j = 0; j < 8; ++j) {
                const float4 k4 = *(const float4*)&Kt[cg + (j << 3)][ch << 2];
                acc[0][j]  = FMA4(qa,  k4, acc[0][j]);
                accn[0][j] = FMA4(na,  k4, accn[0][j]);
                acc[1][j]  = FMA4(qb4, k4, acc[1][j]);
                accn[1][j] = FMA4(nb4, k4, accn[1][j]);
            }
        }

        // active-mask + novelty preamble, then batch top-16 merge per row
        float sq[2][8];
        #pragma unroll
        for (int j = 0; j < 8; ++j) {
            const int ml = cg + (j << 3);
            const bool act = Sm[ml] > 0.f;
            sq[0][j] = act ? acc[0][j] : NEGV;
            sq[1][j] = act ? acc[1][j] : NEGV;
            nsim[0] = fmaxf(nsim[0], act ? accn[0][j] : -1.0f);
            nsim[1] = fmaxf(nsim[1], act ? accn[1][j] : -1.0f);
        }

        #pragma unroll
        for (int rr = 0; rr < 2; ++rr) {
            float bmax = sq[rr][0];
            #pragma unroll
            for (int j = 1; j < 8; ++j) bmax = fmaxf(bmax, sq[rr][j]);
            if (bmax > lv[rr][15]) {
                float bv[8]; int bi[8];
                #pragma unroll
                for (int j = 0; j < 8; ++j) {
                    bv[j] = sq[rr][j];
                    bi[j] = mt*64 + cg + (j << 3);
                }
                // Batcher OEMS-8, descending (19 CE)
                CEB(0,1) CEB(2,3) CEB(4,5) CEB(6,7)
                CEB(0,2) CEB(1,3) CEB(4,6) CEB(5,7)
                CEB(1,2) CEB(5,6)
                CEB(0,4) CEB(1,5) CEB(2,6) CEB(3,7)
                CEB(2,4) CEB(3,5)
                CEB(1,2) CEB(3,4) CEB(5,6)
                // half-cleaner keep-merge: new bottom-8 = top-8 of
                // {old bottom-8 ∪ batch}  (exact top-16 multiset)
                #pragma unroll
                for (int i = 0; i < 8; ++i) {
                    const bool tk = bv[7-i] > lv[rr][8+i];
                    if (tk) { lv[rr][8+i] = bv[7-i]; li[rr][8+i] = bi[7-i]; }
                }
                // bottom half is bitonic -> sort desc (12 CE)
                CEL(8,12) CEL(9,13) CEL(10,14) CEL(11,15)
                CEL(8,10) CEL(9,11) CEL(12,14) CEL(13,15)
                CEL(8,9)  CEL(10,11) CEL(12,13) CEL(14,15)
                // merge two sorted-desc halves -> fully sorted 16 (32 CE)
                CEL(0,15) CEL(1,14) CEL(2,13) CEL(3,12)
                CEL(4,11) CEL(5,10) CEL(6,9)  CEL(7,8)
                CEL(0,4) CEL(1,5) CEL(2,6) CEL(3,7)
                CEL(0,2) CEL(1,3) CEL(4,6) CEL(5,7)
                CEL(0,1) CEL(2,3) CEL(4,5) CEL(6,7)
                CEL(8,12) CEL(9,13) CEL(10,14) CEL(11,15)
                CEL(8,10) CEL(9,11) CEL(12,14) CEL(13,15)
                CEL(8,9)  CEL(10,11) CEL(12,13) CEL(14,15)
            }
        }
    }
#undef CEB
#undef CEL

    // ---- per-row merge of 8 sorted lists -> softmax weights + P.V ----
    const float* Vb = emV + (size_t)sb*MM*DD;

    #pragma unroll
    for (int rr = 0; rr < 2; ++rr) {
        float m0 = 0.f, den = 0.f, wkA = 0.f, wkB = 0.f;
        int ikA = 0, ikB = 0;
        #pragma unroll 1
        for (int k = 0; k < 16; ++k) {
            float cb = lv[rr][0]; int ci2 = li[rr][0]; int key = cg;
            #pragma unroll
            for (int off = 4; off >= 1; off >>= 1) {
                const float ov = __shfl_xor(cb, off, 8);
                const int   ok = __shfl_xor(key, off, 8);
                const int   oi = __shfl_xor(ci2, off, 8);
                if (ov > cb || (ov == cb && ok < key)) { cb = ov; key = ok; ci2 = oi; }
            }
            if (k == 0) m0 = cb;
            const float e = __expf(cb - m0);
            den += e;
            if (key == cg) {   // this lane's head won: pop it
                #pragma unroll
                for (int i = 0; i < 15; ++i) {
                    lv[rr][i] = lv[rr][i+1]; li[rr][i] = li[rr][i+1];
                }
            }
            if ((k & 7) == cg) {
                if (k < 8) { wkA = e; ikA = ci2; }
                else       { wkB = e; ikB = ci2; }
            }
        }

        // novelty: max sim across the group
        float ns = nsim[rr];
        #pragma unroll
        for (int off = 4; off >= 1; off >>= 1)
            ns = fmaxf(ns, __shfl_xor(ns, off, 8));

        // P.V gather: this lane covers d in [cg*8, cg*8+8)
        const float invden = 1.0f / den;
        float4 oA = make_float4(0.f, 0.f, 0.f, 0.f);
        float4 oB = make_float4(0.f, 0.f, 0.f, 0.f);
        #pragma unroll 1
        for (int k = 0; k < 16; ++k) {
            const bool hi = k >= 8;
            const float wsrc = hi ? wkB : wkA;
            const int   isrc = hi ? ikB : ikA;
            const float wv = __shfl(wsrc, k & 7, 8);
            const int   iv = __shfl(isrc, k & 7, 8);
            const float* vp = Vb + (size_t)iv*DD + (cg << 3);
            const float4 va  = *(const float4*)vp;
            const float4 vb2 = *(const float4*)(vp + 4);
            oA.x = fmaf(wv, va.x, oA.x);  oA.y = fmaf(wv, va.y, oA.y);
            oA.z = fmaf(wv, va.z, oA.z);  oA.w = fmaf(wv, va.w, oA.w);
            oB.x = fmaf(wv, vb2.x, oB.x); oB.y = fmaf(wv, vb2.y, oB.y);
            oB.z = fmaf(wv, vb2.z, oB.z); oB.w = fmaf(wv, vb2.w, oB.w);
        }
        oA.x *= invden; oA.y *= invden; oA.z *= invden; oA.w *= invden;
        oB.x *= invden; oB.y *= invden; oB.z *= invden; oB.w *= invden;
        const size_t ob = (((size_t)s*NN + n0 + r0 + rr)*BH + b)*DD + (cg << 3);
        *(float4*)&out[ob]     = oA;
        *(float4*)&out[ob + 4] = oB;

        if (cg == 0) {
            const int ni = ((s*NN + n0 + r0 + rr)*BH) + b;
            const float w = wnov[ni], su = surprise[ni];
            ws[WS_NOV + sb*NN + n0 + r0 + rr] =
                w*su + (1.f - w)*(1.f - fmaxf(ns, 0.f));
        }
    }
}

// ---------------------------------------------------------------------------
// Kernel 2: per (s,b) top-64 of novelty over N=1024 + cand_weight.
// Single-wave tournament (no barriers).
// ---------------------------------------------------------------------------
__global__ __launch_bounds__(64)
void k2_topc(float* __restrict__ ws)
{
    const int sb = blockIdx.x;
    const int lane = threadIdx.x;          // 0..63
    float av[16]; int ai[16];
    const int base = WS_NOV + sb*NN + lane*16;
    #pragma unroll
    for (int j = 0; j < 16; ++j) { av[j] = ws[base + j]; ai[j] = lane*16 + j; }

    // odd-even transposition sort: descending value, ascending index on ties
    #pragma unroll
    for (int pass = 0; pass < 16; ++pass) {
        #pragma unroll
        for (int i = (pass & 1); i + 1 < 16; i += 2) {
            const bool sw = (av[i] < av[i+1]) ||
                            (av[i] == av[i+1] && ai[i] > ai[i+1]);
            const float t0 = sw ? av[i+1] : av[i];
            const float t1 = sw ? av[i]   : av[i+1];
            av[i] = t0; av[i+1] = t1;
            const int u0 = sw ? ai[i+1] : ai[i];
            const int u1 = sw ? ai[i]   : ai[i+1];
            ai[i] = u0; ai[i+1] = u1;
        }
    }

    float kv = 0.f; int ki = 0;
    #pragma unroll 1
    for (int k = 0; k < CC; ++k) {
        float lv2 = av[0]; int key = lane;
        #pragma unroll
        for (int off = 32; off >= 1; off >>= 1) {
            const float ov = __shfl_xor(lv2, off, 64);
            const int   ok = __shfl_xor(key, off, 64);
            if (ov > lv2 || (ov == lv2 && ok < key)) { lv2 = ov; key = ok; }
        }
        const int widx = __shfl(ai[0], key, 64);
        if (lane == k) { kv = lv2; ki = widx; }
        if (lane == key) {
            #pragma unroll
            for (int i = 0; i < 15; ++i) { av[i] = av[i+1]; ai[i] = ai[i+1]; }
            av[15] = -3.0e38f;
        }
    }

    float sum = kv;
    #pragma unroll
    for (int off = 32; off >= 1; off >>= 1) sum += __shfl_xor(sum, off, 64);
    ((int*)ws)[WS_CI + sb*CC + lane] = ki;
    ws[WS_CW + sb*CC + lane] = kv / (sum + EPSV);
}

// ---------------------------------------------------------------------------
// Kernel 3a: gather cand_K/cand_V, unit-normalize cand_K
// ---------------------------------------------------------------------------
__global__ __launch_bounds__(256)
void k3a_gather(const float* __restrict__ qn, const float* __restrict__ vn,
                float* __restrict__ ws)
{
    const int sb = blockIdx.x; const int s = sb >> 3, b = sb & 7;
    const int t = threadIdx.x;
    const int cc = t >> 2, qd = t & 3;
    const int idx = ((const int*)ws)[WS_CI + sb*CC + cc];
    const size_t base = (((size_t)s*NN + idx)*BH + b)*DD + qd*16;

    float4 a[4]; float ss = 0.f;
    #pragma unroll
    for (int k = 0; k < 4; ++k) {
        a[k] = *(const float4*)&qn[base + (k << 2)];
        ss = fmaf(a[k].x, a[k].x, ss); ss = fmaf(a[k].y, a[k].y, ss);
        ss = fmaf(a[k].z, a[k].z, ss); ss = fmaf(a[k].w, a[k].w, ss);
    }
    #pragma unroll
    for (int off = 2; off >= 1; off >>= 1) ss += __shfl_xor(ss, off, 4);
    const float sc = 1.0f / fmaxf(sqrtf(ss), EPSV);

    float* ck = ws + WS_CKN + ((size_t)sb*CC + cc)*DD + qd*16;
    float* cv = ws + WS_CV  + ((size_t)sb*CC + cc)*DD + qd*16;
    #pragma unroll
    for (int k = 0; k < 4; ++k) {
        float4 o = a[k]; o.x *= sc; o.y *= sc; o.z *= sc; o.w *= sc;
        *(float4*)&ck[k << 2] = o;
        *(float4*)&cv[k << 2] = *(const float4*)&vn[base + (k << 2)];
    }
}

// ---------------------------------------------------------------------------
// Kernel 3b: slot-softmax partial stats.
// grid (32,16); each block = 64 cands x 128 m GEMM tile with K staged once
// in LDS; online-softmax partials to ws, combined in k3c's prologue.
// ---------------------------------------------------------------------------
__global__ __launch_bounds__(256)
void k3b_stats(const float* __restrict__ emK, const float* __restrict__ emS,
               const float* __restrict__ tau, const float* __restrict__ wwp,
               float* __restrict__ ws)
{
    const int sb = blockIdx.x;
    const int mc = blockIdx.y;           // m-chunk of 128
    const int t = threadIdx.x;
    const int rg = t >> 3, cg = t & 7;
    const int c0 = rg << 1;

    __shared__ float ckL[64][68];
    __shared__ float Kt[64][68];
    __shared__ float Sm[64];

    #pragma unroll
    for (int k = 0; k < 4; ++k) {
        const int fi = t + (k << 8);
        const int row = fi >> 4;
        const int col = (fi & 15) << 2;
        *(float4*)&ckL[row][col] =
            *(const float4*)&ws[WS_CKN + ((size_t)sb*CC + row)*DD + col];
    }

    const float invt = 1.0f / fmaxf(tau[sb], 0.01f);
    const float wwv = wwp[sb];
    const float* Kb = emK + (size_t)sb*MM*DD;
    const float* Sb = emS + (size_t)sb*MM;

    float rmax[2] = {-3.0e38f, -3.0e38f};
    float rsum[2] = {0.f, 0.f};

    #pragma unroll 1
    for (int tt = 0; tt < 2; ++tt) {
        const int mb = (mc << 7) + (tt << 6);
        __syncthreads();
        #pragma unroll
        for (int k = 0; k < 4; ++k) {
            const int fi = t + (k << 8);
            const int row = fi >> 4;
            const int col = (fi & 15) << 2;
            *(float4*)&Kt[row][col] = *(const float4*)&Kb[((size_t)(mb + row))*DD + col];
        }
        if (t < 64) Sm[t] = Sb[mb + t];
        __syncthreads();

        float acc[2][8];
        #pragma unroll
        for (int rr = 0; rr < 2; ++rr)
            #pragma unroll
            for (int j = 0; j < 8; ++j) acc[rr][j] = 0.f;

        #pragma unroll 4
        for (int ch = 0; ch < 16; ++ch) {
            const float4 ca = *(const float4*)&ckL[c0][ch << 2];
            const float4 cb = *(const float4*)&ckL[c0 + 1][ch << 2];
            #pragma unroll
            for (int j = 0; j < 8; ++j) {
                const float4 k4 = *(const float4*)&Kt[cg + (j << 3)][ch << 2];
                acc[0][j] = FMA4(ca, k4, acc[0][j]);
                acc[1][j] = FMA4(cb, k4, acc[1][j]);
            }
        }

        #pragma unroll
        for (int rr = 0; rr < 2; ++rr) {
            float z[8];
            #pragma unroll
            for (int j = 0; j < 8; ++j)
                z[j] = (acc[rr][j] - wwv*Sm[cg + (j << 3)]) * invt;
            float tmax = z[0];
            #pragma unroll
            for (int j = 1; j < 8; ++j) tmax = fmaxf(tmax, z[j]);
            #pragma unroll
            for (int off = 4; off >= 1; off >>= 1)
                tmax = fmaxf(tmax, __shfl_xor(tmax, off, 8));
            const float nm = fmaxf(rmax[rr], tmax);
            float ts = 0.f;
            #pragma unroll
            for (int j = 0; j < 8; ++j) ts += __expf(z[j] - nm);
            #pragma unroll
            for (int off = 4; off >= 1; off >>= 1) ts += __shfl_xor(ts, off, 8);
            rsum[rr] = rsum[rr]*__expf(rmax[rr] - nm) + ts;
            rmax[rr] = nm;
        }
    }
    if (cg == 0) {
        #pragma unroll
        for (int rr = 0; rr < 2; ++rr) {
            ws[WS_PMAX + ((size_t)sb*CC + c0 + rr)*16 + mc] = rmax[rr];
            ws[WS_PSUM + ((size_t)sb*CC + c0 + rr)*16 + mc] = rsum[rr];
        }
    }
}

// ---------------------------------------------------------------------------
// Kernel 3c: per (s,b, 64-m tile): alpha, alpha_per_slot, blends, updates
// ---------------------------------------------------------------------------
__global__ __launch_bounds__(256)
void k3c_write(const float* __restrict__ emK, const float* __restrict__ emV,
               const float* __restrict__ emS, const float* __restrict__ emA,
               const float* __restrict__ gem, const float* __restrict__ tau,
               const float* __restrict__ dec, const float* __restrict__ wwp,
             float* __restrict__ outK, float* __restrict__ outV,
             float* __restrict__ outS, float* __restrict__ outA,
             float* __restrict__ ws)
{
    const int sb = blockIdx.x; const int m0 = blockIdx.y << 6;
    const int t = threadIdx.x;
    __shared__ float ckn[64][68];
    __shared__ float cvv[64][68];
    __shared__ float alphaT[64][64];   // [c][m]
    __shared__ float apsL[64];
    __shared__ float psum[4][64];
    __shared__ float pn[4][64];
    __shared__ float mx[64], gs[64], Sl[64];

    const float gv  = gem[sb];
    const float invt = 1.0f / fmaxf(tau[sb], 0.01f);
    const float wwv = wwp[sb];
    const float dcv = dec[sb];

    #pragma unroll
    for (int k = 0; k < 4; ++k) {
        const int fid = t + (k << 8);
        const int row = fid >> 4;
        const int col = (fid & 15) << 2;
        *(float4*)&ckn[row][col] = *(const float4*)&ws[WS_CKN + ((size_t)sb*CC + row)*DD + col];
        *(float4*)&cvv[row][col] = *(const float4*)&ws[WS_CV  + ((size_t)sb*CC + row)*DD + col];
    }
    if (t < 64) {
        // combine slot-softmax partials
        float mg = -3.0e38f;
        #pragma unroll
        for (int p = 0; p < 16; ++p)
            mg = fmaxf(mg, ws[WS_PMAX + ((size_t)sb*CC + t)*16 + p]);
        float sg = 0.f;
        #pragma unroll
        for (int p = 0; p < 16; ++p)
            sg += ws[WS_PSUM + ((size_t)sb*CC + t)*16 + p] *
                  __expf(ws[WS_PMAX + ((size_t)sb*CC + t)*16 + p] - mg);
        const float cw = ws[WS_CW + sb*CC + t];
        mx[t] = mg;
        gs[t] = gv * cw / sg;
        Sl[t] = emS[(size_t)sb*MM + m0 + t];
    }
    __syncthreads();

    const int m = t & 63, w = t >> 6;

    // step 1: alphaT[c][m] for this wave's 16 c's
    {
        float acc[16];
        #pragma unroll
        for (int i = 0; i < 16; ++i) acc[i] = 0.f;
        const float* Krow = emK + ((size_t)sb*MM + m0 + m)*DD;
        #pragma unroll 4
        for (int ch = 0; ch < 16; ++ch) {
            const float4 k4 = *(const float4*)&Krow[ch << 2];
            #pragma unroll
            for (int i = 0; i < 16; ++i) {
                const float4 c4 = *(const float4*)&ckn[(w << 4) + i][ch << 2];
                acc[i] = FMA4(k4, c4, acc[i]);
            }
        }
        const float Sv = Sl[m];
        #pragma unroll
        for (int i = 0; i < 16; ++i) {
            const int c = (w << 4) + i;
            const float zz = (acc[i] - wwv*Sv) * invt;
            alphaT[c][m] = gs[c] * __expf(zz - mx[c]);
        }
    }
    __syncthreads();

    // step 2: alpha_per_slot
    {
        float p = 0.f;
        #pragma unroll
        for (int i = 0; i < 16; ++i) p += alphaT[(w << 4) + i][m];
        psum[w][m] = p;
    }
    __syncthreads();
    if (t < 64) apsL[t] = (psum[0][t] + psum[1][t]) + (psum[2][t] + psum[3][t]);
    __syncthreads();

    // step 3: blends — this thread covers d in [w*16, w*16+16)
    float bk[16], bv[16];
    #pragma unroll
    for (int i = 0; i < 16; ++i) { bk[i] = 0.f; bv[i] = 0.f; }
    for (int cI = 0; cI < 64; ++cI) {
        const float a = alphaT[cI][m];
        #pragma unroll
        for (int k = 0; k < 4; ++k) {
            const float4 c4 = *(const float4*)&ckn[cI][(w << 4) + (k << 2)];
            const float4 v4 = *(const float4*)&cvv[cI][(w << 4) + (k << 2)];
            bk[(k<<2)+0] = fmaf(a, c4.x, bk[(k<<2)+0]);
            bk[(k<<2)+1] = fmaf(a, c4.y, bk[(k<<2)+1]);
            bk[(k<<2)+2] = fmaf(a, c4.z, bk[(k<<2)+2]);
            bk[(k<<2)+3] = fmaf(a, c4.w, bk[(k<<2)+3]);
            bv[(k<<2)+0] = fmaf(a, v4.x, bv[(k<<2)+0]);
            bv[(k<<2)+1] = fmaf(a, v4.y, bv[(k<<2)+1]);
            bv[(k<<2)+2] = fmaf(a, v4.z, bv[(k<<2)+2]);
            bv[(k<<2)+3] = fmaf(a, v4.w, bv[(k<<2)+3]);
        }
    }

    // step 4: normalize + update
    const float aps = apsL[m];
    const float idn = 1.0f / fmaxf(aps, EPSV);
    float ssq = 0.f;
    #pragma unroll
    for (int i = 0; i < 16; ++i) { bk[i] *= idn; bv[i] *= idn; ssq = fmaf(bk[i], bk[i], ssq); }
    pn[w][m] = ssq;
    __syncthreads();
    const float nrm2 = (pn[0][m] + pn[1][m]) + (pn[2][m] + pn[3][m]);
    const float innv = 1.0f / fmaxf(sqrtf(nrm2), EPSV);
    const float ae = fminf(aps, 1.0f);
    const float oma = 1.0f - ae;
    const bool upd = aps > EPSV;
    const size_t gb = ((size_t)sb*MM + m0 + m)*DD + (w << 4);
    #pragma unroll
    for (int kq = 0; kq < 4; ++kq) {
        const float4 kk = *(const float4*)&emK[gb + (kq << 2)];
        const float4 vv = *(const float4*)&emV[gb + (kq << 2)];
        float4 nk, nv2;
        if (upd) {
            nk.x = oma*kk.x + ae*(bk[(kq<<2)+0]*innv);
            nk.y = oma*kk.y + ae*(bk[(kq<<2)+1]*innv);
            nk.z = oma*kk.z + ae*(bk[(kq<<2)+2]*innv);
            nk.w = oma*kk.w + ae*(bk[(kq<<2)+3]*innv);
            nv2.x = oma*vv.x + ae*bv[(kq<<2)+0];
            nv2.y = oma*vv.y + ae*bv[(kq<<2)+1];
            nv2.z = oma*vv.z + ae*bv[(kq<<2)+2];
            nv2.w = oma*vv.w + ae*bv[(kq<<2)+3];
        } else { nk = kk; nv2 = vv; }
        *(float4*)&outK[gb + (kq << 2)] = nk;
        *(float4*)&outV[gb + (kq << 2)] = nv2;
    }
    if (w == 0) {
        const float pre = fminf(fmaxf(Sl[m] + aps, 0.f), SMAXV) * dcv;
        outS[(size_t)sb*MM + m0 + m] = pre;
        outA[(size_t)sb*MM + m0 + m] = emA[(size_t)sb*MM + m0 + m] * (1.0f - aps);
        float tot = pre;
        #pragma unroll
        for (int off = 32; off >= 1; off >>= 1) tot += __shfl_xor(tot, off, 64);
        if (m == 0) atomicAdd(&ws[WS_TOTS + sb], tot);
    }
}

// ---------------------------------------------------------------------------
// Kernel 4: budget rescale of new_S
// ---------------------------------------------------------------------------
__global__ __launch_bounds__(256)
void k4_budget(float* __restrict__ outS, const float* __restrict__ ws)
{
    const int sb = blockIdx.x;
    const float sc = fminf(1.0f, BUDGETV / (ws[WS_TOTS + sb] + EPSV));
    for (int m = threadIdx.x; m < MM; m += 256)
        outS[(size_t)sb*MM + m] *= sc;
}

extern "C" void kernel_launch(void* const* d_in, const int* in_sizes, int n_in,
                              void* d_out, int out_size, void* d_ws, size_t ws_size,
                              hipStream_t stream)
{
    const float* q   = (const float*)d_in[0];
    const float* qnv = (const float*)d_in[1];
    const float* vnv = (const float*)d_in[2];
    const float* sur = (const float*)d_in[3];
    const float* wn  = (const float*)d_in[4];
    const float* gem = (const float*)d_in[5];
    const float* tau = (const float*)d_in[6];
    const float* dec = (const float*)d_in[7];
    const float* wwp = (const float*)d_in[8];
    const float* emK = (const float*)d_in[9];
    const float* emV = (const float*)d_in[10];
    const float* emS = (const float*)d_in[11];
    const float* emA = (const float*)d_in[12];

    float* out  = (float*)d_out;
    float* outK = out + 2097152;
    float* outV = out + 6291456;
    float* outS = out + 10485760;
    float* outA = out + 10551296;
    float* ws = (float*)d_ws;

    hipMemsetAsync((char*)d_ws + WS_TOTS*sizeof(float), 0, 32*sizeof(float), stream);

    k1_read<<<dim3(32, 16), 256, 0, stream>>>(q, qnv, sur, wn, emK, emV, emS, out, ws);
    k2_topc<<<32, 64, 0, stream>>>(ws);
    k3a_gather<<<32, 256, 0, stream>>>(qnv, vnv, ws);
    k3b_stats<<<dim3(32, 16), 256, 0, stream>>>(emK, emS, tau, wwp, ws);
    k3c_write<<<dim3(32, 32), 256, 0, stream>>>(emK, emV, emS, emA, gem, tau, dec, wwp,
                                                outK, outV, outS, outA, ws);
    k4_budget<<<32, 256, 0, stream>>>(outS, ws);
}